// Round 13
// baseline (29.738 us; speedup 1.0000x reference)
//
#include <hip/hip_runtime.h>
#include <hip/hip_bf16.h>

#define L_CLS 2048
#define D_DIM 512
#define T_SZ  512
#define NT    511              // T-1 transitions per sequence
#define NOUT  (64 * NT)        // 32704
#define NCHUNK 32              // 64-col sum granularity (2 per 128-col block)
#define LDSS  136              // LDS row stride in elems (272 B)
#define LOG2E 1.4426950408889634f
#define LN2   0.6931471805599453f
#define SHIFT 128.0f           // fixed exponent shift: sum 2^(x*log2e - SHIFT)

typedef __attribute__((ext_vector_type(8)))  short bf16x8;
typedef __attribute__((ext_vector_type(4)))  float f32x4;
typedef __attribute__((ext_vector_type(16))) float f32x16;

static __device__ __forceinline__ short f2bf(float x) {
    return (short)__bfloat16_as_ushort(__float2bfloat16(x));
}

// ---------------------------------------------------------------- conv kernel
__global__ void conv_bf16(const float* __restrict__ srcE, const float* __restrict__ tgtE,
                          __hip_bfloat16* __restrict__ Sb, __hip_bfloat16* __restrict__ Tb) {
    int i = blockIdx.x * blockDim.x + threadIdx.x;   // groups of 8
    if (i >= (L_CLS * D_DIM) / 8) return;
    const f32x4* s4 = reinterpret_cast<const f32x4*>(srcE) + i * 2;
    const f32x4* t4 = reinterpret_cast<const f32x4*>(tgtE) + i * 2;
    f32x4 s0 = s4[0], s1 = s4[1];
    f32x4 t0 = t4[0], t1 = t4[1];
    bf16x8 so, to;
#pragma unroll
    for (int j = 0; j < 4; ++j) {
        so[j] = f2bf(s0[j]); so[j + 4] = f2bf(s1[j]);
        to[j] = f2bf(t0[j]); to[j + 4] = f2bf(t1[j]);
    }
    reinterpret_cast<bf16x8*>(Sb)[i] = so;
    reinterpret_cast<bf16x8*>(Tb)[i] = to;
}

// ------------------------------------------- bf16 GEMM (32x32x16) + sums + M
// grid (16,16) x 512 thr (8 waves). Wave w: 32-row stripe (w&3)*32 within the
// 128-row block, 64-col half (w>>2)*64 within the 128-col chunk. acc = 2 x
// f32x16 (ct=0,1 -> 32-col subtiles). Double-buffered LDS B staging: slice
// s+1 global->reg prefetch under s's MFMAs, ds_write to buf^1 after MFMAs,
// ONE barrier per slice. 32x32x16 halves ds_read and MFMA instr count vs
// 16x16x32 for the same FLOPs (1 b128 B-frag per 32768 FLOP).
__launch_bounds__(512, 1)
__global__ void gemm_lse_bf16(const __hip_bfloat16* __restrict__ Sb,
                              const __hip_bfloat16* __restrict__ Tb,
                              float* __restrict__ psum,
                              float* __restrict__ M) {
    __shared__ __hip_bfloat16 Blds[2][128 * LDSS];   // 2 x 34816 B

    const int tid  = threadIdx.x;
    const int wave = tid >> 6;           // 0..7
    const int lane = tid & 63;
    const int l31  = lane & 31;          // A-row / B-col within 32
    const int hk   = lane >> 5;          // k-group (0: k0-7, 1: k8-15)
    const int rs   = (wave & 3) * 32;    // row stripe
    const int chf  = wave >> 2;          // col half 0/1
    const int C    = blockIdx.x * 128;
    const int Rb   = blockIdx.y * 128;
    const int Ar   = Rb + rs + l31;      // this lane's A row

    f32x16 acc0, acc1;
#pragma unroll
    for (int r = 0; r < 16; ++r) { acc0[r] = 0.f; acc1[r] = 0.f; }

    bf16x8 stg[4], an[8];
    // prologue: slice 0 B-chunk + A-frags
#pragma unroll
    for (int i = 0; i < 4; ++i) {
        int p = tid + 512 * i;           // 0..2047: row p>>4, 16B-chunk p&15
        stg[i] = *reinterpret_cast<const bf16x8*>(
            &Tb[(C + (p >> 4)) * D_DIM + (p & 15) * 8]);
    }
#pragma unroll
    for (int ks = 0; ks < 8; ++ks)
        an[ks] = *reinterpret_cast<const bf16x8*>(
            &Sb[Ar * D_DIM + ks * 16 + hk * 8]);
#pragma unroll
    for (int i = 0; i < 4; ++i) {
        int p = tid + 512 * i;
        *reinterpret_cast<bf16x8*>(&Blds[0][(p >> 4) * LDSS + (p & 15) * 8]) = stg[i];
    }
    __syncthreads();

#pragma unroll
    for (int s = 0; s < 4; ++s) {
        const int cur = s & 1;
        bf16x8 a[8];
#pragma unroll
        for (int ks = 0; ks < 8; ++ks) a[ks] = an[ks];

        if (s < 3) {   // prefetch next slice into regs (flies under MFMAs)
#pragma unroll
            for (int i = 0; i < 4; ++i) {
                int p = tid + 512 * i;
                stg[i] = *reinterpret_cast<const bf16x8*>(
                    &Tb[(C + (p >> 4)) * D_DIM + (s + 1) * 128 + (p & 15) * 8]);
            }
#pragma unroll
            for (int ks = 0; ks < 8; ++ks)
                an[ks] = *reinterpret_cast<const bf16x8*>(
                    &Sb[Ar * D_DIM + (s + 1) * 128 + ks * 16 + hk * 8]);
        }

        const __hip_bfloat16* Bb = Blds[cur];
#pragma unroll
        for (int ks = 0; ks < 8; ++ks) {
            const int off = ks * 16 + hk * 8;
            bf16x8 b0 = *reinterpret_cast<const bf16x8*>(&Bb[(chf * 64 + l31) * LDSS + off]);
            bf16x8 b1 = *reinterpret_cast<const bf16x8*>(&Bb[(chf * 64 + 32 + l31) * LDSS + off]);
            acc0 = __builtin_amdgcn_mfma_f32_32x32x16_bf16(a[ks], b0, acc0, 0, 0, 0);
            acc1 = __builtin_amdgcn_mfma_f32_32x32x16_bf16(a[ks], b1, acc1, 0, 0, 0);
        }

        if (s < 3) {   // write next slice to the other buffer; one barrier
#pragma unroll
            for (int i = 0; i < 4; ++i) {
                int p = tid + 512 * i;
                *reinterpret_cast<bf16x8*>(
                    &Blds[cur ^ 1][(p >> 4) * LDSS + (p & 15) * 8]) = stg[i];
            }
            __syncthreads();
        }
    }

    // ---- epilogue: M writes + fixed-shift exp sums ----
    // C/D layout (verified m74/m101): col = lane&31, row = (reg&3)+8*(reg>>2)+4*hk
    float p[16];
#pragma unroll
    for (int r = 0; r < 16; ++r) {
        int grow = Rb + rs + (r & 3) + 8 * (r >> 2) + 4 * hk;
        size_t base = (size_t)grow * L_CLS + C + chf * 64 + l31;
        M[base]      = acc0[r];
        M[base + 32] = acc1[r];
        p[r] = exp2f(acc0[r] * LOG2E - SHIFT) + exp2f(acc1[r] * LOG2E - SHIFT);
    }
#pragma unroll
    for (int off = 1; off < 32; off <<= 1)
#pragma unroll
        for (int r = 0; r < 16; ++r) p[r] += __shfl_xor(p[r], off);
    if (l31 == 0) {
#pragma unroll
        for (int r = 0; r < 16; ++r) {
            int grow = Rb + rs + (r & 3) + 8 * (r >> 2) + 4 * hk;
            psum[grow * NCHUNK + blockIdx.x * 2 + chf] = p[r];
        }
    }
}

// -------------------------------------------------------------- gather scores
__launch_bounds__(256)
__global__ void scores_gather(const int* __restrict__ labels,
                              const float* __restrict__ psum,
                              const float* __restrict__ M,
                              float* __restrict__ out) {
    int o = blockIdx.x * 256 + threadIdx.x;
    if (o >= NOUT) return;
    int b = o / NT;
    int t = o - b * NT;
    int src = labels[b * T_SZ + t];
    int tgt = labels[b * T_SZ + t + 1];

    const f32x4* pv = reinterpret_cast<const f32x4*>(psum + src * NCHUNK);
    f32x4 sv = pv[0];
#pragma unroll
    for (int c = 1; c < NCHUNK / 4; ++c) {
        f32x4 v = pv[c];
        sv[0] += v[0]; sv[1] += v[1]; sv[2] += v[2]; sv[3] += v[3];
    }
    float S = (sv[0] + sv[1]) + (sv[2] + sv[3]);
    float lse = (log2f(S) + SHIFT) * LN2;
    out[o] = M[(size_t)src * L_CLS + tgt] - lse;
}

// ------------------------------------------------------------------- launcher
extern "C" void kernel_launch(void* const* d_in, const int* in_sizes, int n_in,
                              void* d_out, int out_size, void* d_ws, size_t ws_size,
                              hipStream_t stream) {
    const int*   labels = (const int*)d_in[0];
    const float* srcE   = (const float*)d_in[1];
    const float* tgtE   = (const float*)d_in[2];
    float*       out    = (float*)d_out;

    const size_t tbl = (size_t)L_CLS * D_DIM;
    __hip_bfloat16* Sb = (__hip_bfloat16*)d_ws;                    // 2 MB
    __hip_bfloat16* Tb = Sb + tbl;                                 // 2 MB
    float* psum = (float*)((char*)d_ws + 2 * tbl * sizeof(__hip_bfloat16)); // 256 KB
    float* M    = psum + (size_t)L_CLS * NCHUNK;                   // 16 MB

    conv_bf16<<<(int)(tbl / 8 + 255) / 256, 256, 0, stream>>>(srcE, tgtE, Sb, Tb);
    gemm_lse_bf16<<<dim3(16, 16), 512, 0, stream>>>(Sb, Tb, psum, M);
    scores_gather<<<(NOUT + 255) / 256, 256, 0, stream>>>(labels, psum, M, out);
}